// Round 13
// baseline (1419.540 us; speedup 1.0000x reference)
//
#include <hip/hip_runtime.h>

#define NN   16384
#define DIM  256
#define KNN  16
#define SEG  8
#define JT_PER (NN / SEG / 128)   // 16 column tiles per segment

typedef __attribute__((ext_vector_type(8))) short  bf16x8;
typedef __attribute__((ext_vector_type(4))) float  f32x4;

// ======================================================================
// async global->LDS 16B helper (linear LDS dest, per-lane global source)
// ======================================================================
__device__ __forceinline__ void gload_lds16b(const unsigned short* g, void* l)
{
    __builtin_amdgcn_global_load_lds(
        (const __attribute__((address_space(1))) unsigned int*)g,
        (__attribute__((address_space(3))) unsigned int*)l, 16, 0, 0);
}

// float -> bf16 (RNE, finite inputs)
__device__ __forceinline__ unsigned short f2bf(float x)
{
    unsigned int u = __float_as_uint(x);
    unsigned int r = (u + 0x7fffu + ((u >> 16) & 1u)) >> 16;
    return (unsigned short)r;
}
__device__ __forceinline__ float bf2f(unsigned short u)
{
    return __uint_as_float(((unsigned)u) << 16);
}

// pack (distance, col) into one sortable u32: 18 d-bits | 14 j-bits
__device__ __forceinline__ unsigned pack_key(float d, int j)
{
    return (__float_as_uint(fmaxf(d, 0.0f)) & 0xFFFFC000u) | (unsigned)j;
}

// ======================================================================
// fp32 -> bf16 convert
// ======================================================================
__global__ __launch_bounds__(256)
void convert_bf16_k(const float* __restrict__ in, unsigned short* __restrict__ out)
{
    const int i4 = blockIdx.x * 256 + threadIdx.x;
    float4 v = *(const float4*)&in[(size_t)i4 * 4];
    ushort4 b;
    b.x = f2bf(v.x); b.y = f2bf(v.y); b.z = f2bf(v.z); b.w = f2bf(v.w);
    *(ushort4*)&out[(size_t)i4 * 4] = b;
}

// fp32 -> (hi, lo) bf16 split: v ~= hi + lo
__global__ __launch_bounds__(256)
void convert_hilo_k(const float* __restrict__ in,
                    unsigned short* __restrict__ hi, unsigned short* __restrict__ lo)
{
    const int i4 = blockIdx.x * 256 + threadIdx.x;
    float4 v = *(const float4*)&in[(size_t)i4 * 4];
    ushort4 h, l;
    h.x = f2bf(v.x); l.x = f2bf(v.x - bf2f(h.x));
    h.y = f2bf(v.y); l.y = f2bf(v.y - bf2f(h.y));
    h.z = f2bf(v.z); l.z = f2bf(v.z - bf2f(h.z));
    h.w = f2bf(v.w); l.w = f2bf(v.w - bf2f(h.w));
    *(ushort4*)&hi[(size_t)i4 * 4] = h;
    *(ushort4*)&lo[(size_t)i4 * 4] = l;
}

// ======================================================================
// Split-bf16 MFMA pre-GEMM:  h0 = relu( (xh+xl) @ (Wh+Wl)^T + b )
// = xh*Wh + xl*Wh + xh*Wl.  Emits f32 h0 + bf16 shadow.
// ======================================================================
__global__ __launch_bounds__(256, 1)
void pre_mfma(const unsigned short* __restrict__ xh, const unsigned short* __restrict__ xl,
              const unsigned short* __restrict__ wh, const unsigned short* __restrict__ wl,
              const float* __restrict__ bias,
              float* __restrict__ C, unsigned short* __restrict__ Cb)
{
    __shared__ __align__(16) float smem[16896];              // 67.6 KB
    unsigned short* stAh = (unsigned short*)smem;
    unsigned short* stAl = (unsigned short*)((char*)smem + 16384);
    unsigned short* stBh = (unsigned short*)((char*)smem + 32768);
    unsigned short* stBl = (unsigned short*)((char*)smem + 49152);
    float* D = smem;                                         // f32 [128][132]

    const int tid  = threadIdx.x;
    const int lane = tid & 63;
    const int wave = tid >> 6;
    const int wj = wave >> 1;
    const int wi = wave & 1;
    const int l15 = lane & 15;
    const int g   = lane >> 4;
    const int R0 = blockIdx.y * 128;
    const int C0 = blockIdx.x * 128;

    f32x4 acc[4][4];
    #pragma unroll
    for (int fa = 0; fa < 4; ++fa)
        #pragma unroll
        for (int fb = 0; fb < 4; ++fb)
            acc[fa][fb] = (f32x4){0.f, 0.f, 0.f, 0.f};

    #pragma unroll 1
    for (int ch = 0; ch < 4; ++ch) {
        const int k0g = ch * 64;
        __syncthreads();
        #pragma unroll
        for (int it = 0; it < 4; ++it) {
            const int lin = tid + it * 256;
            const int row = lin >> 3, f = lin & 7;
            const int kq = f ^ (row & 7);
            gload_lds16b(&xh[(size_t)(R0 + row) * 256 + k0g + kq * 8], (char*)stAh + lin * 16);
            gload_lds16b(&xl[(size_t)(R0 + row) * 256 + k0g + kq * 8], (char*)stAl + lin * 16);
            gload_lds16b(&wh[(size_t)(C0 + row) * 256 + k0g + kq * 8], (char*)stBh + lin * 16);
            gload_lds16b(&wl[(size_t)(C0 + row) * 256 + k0g + kq * 8], (char*)stBl + lin * 16);
        }
        __syncthreads();

        #pragma unroll
        for (int k0 = 0; k0 < 64; k0 += 32) {
            const int ub = (k0 >> 3) + g;
            bf16x8 afh[4], afl[4], bfh[4], bfl[4];
            #pragma unroll
            for (int q = 0; q < 4; ++q) {
                const int jr = wj*64 + q*16 + l15;
                const int ir = wi*64 + q*16 + l15;
                const int oj = (ub ^ (jr & 7)) * 16;
                const int oi = (ub ^ (ir & 7)) * 16;
                afh[q] = *(const bf16x8*)((char*)stBh + jr*128 + oj);
                afl[q] = *(const bf16x8*)((char*)stBl + jr*128 + oj);
                bfh[q] = *(const bf16x8*)((char*)stAh + ir*128 + oi);
                bfl[q] = *(const bf16x8*)((char*)stAl + ir*128 + oi);
            }
            #pragma unroll
            for (int fa = 0; fa < 4; ++fa)
                #pragma unroll
                for (int fb = 0; fb < 4; ++fb) {
                    acc[fa][fb] = __builtin_amdgcn_mfma_f32_16x16x32_bf16(
                        afh[fa], bfl[fb], acc[fa][fb], 0, 0, 0);
                    acc[fa][fb] = __builtin_amdgcn_mfma_f32_16x16x32_bf16(
                        afl[fa], bfh[fb], acc[fa][fb], 0, 0, 0);
                    acc[fa][fb] = __builtin_amdgcn_mfma_f32_16x16x32_bf16(
                        afh[fa], bfh[fb], acc[fa][fb], 0, 0, 0);
                }
        }
    }

    __syncthreads();
    #pragma unroll
    for (int fa = 0; fa < 4; ++fa)
        #pragma unroll
        for (int fb = 0; fb < 4; ++fb) {
            const int i_ = wi*64 + fb*16 + l15;
            const int j0 = wj*64 + fa*16 + g*4;
            *(f32x4*)&D[i_ * 132 + j0] = acc[fa][fb];
        }
    __syncthreads();

    #pragma unroll
    for (int it = 0; it < 16; ++it) {
        const int linear = it * 256 + tid;
        const int r = linear >> 5, c4 = linear & 31;
        float4 v = *(const float4*)&D[r * 132 + c4 * 4];
        float o[4] = {v.x, v.y, v.z, v.w};
        #pragma unroll
        for (int cc = 0; cc < 4; ++cc) {
            o[cc] += bias[C0 + c4*4 + cc];
            o[cc] = fmaxf(o[cc], 0.0f);
        }
        *(float4*)&C[(size_t)(R0 + r) * 256 + C0 + c4*4] =
            make_float4(o[0], o[1], o[2], o[3]);
        ushort4 bv;
        bv.x = f2bf(o[0]); bv.y = f2bf(o[1]);
        bv.z = f2bf(o[2]); bv.w = f2bf(o[3]);
        *(ushort4*)&Cb[(size_t)(R0 + r) * 256 + C0 + c4*4] = bv;
    }
}

// ======================================================================
// bf16-MFMA GEMM: out = act( rowscale*(Ab @ Wb^T) + bias ), K = 256.
// ======================================================================
template<bool RELU, bool BIAS, bool ROWSCALE, bool F32OUT>
__global__ __launch_bounds__(256, 1)
void gemm_mfma(const unsigned short* __restrict__ Ab, const unsigned short* __restrict__ Wb,
               const float* __restrict__ bias, const float* __restrict__ rscale,
               float* __restrict__ C, unsigned short* __restrict__ Cb, int NO)
{
    __shared__ __align__(16) float smem[25088];            // 98 KB
    unsigned short* stA = (unsigned short*)smem;
    unsigned short* stB = (unsigned short*)(smem + 4096);
    float* D = smem + 8192;

    const int tid  = threadIdx.x;
    const int lane = tid & 63;
    const int wave = tid >> 6;
    const int wj = wave >> 1;
    const int wi = wave & 1;
    const int l15 = lane & 15;
    const int g   = lane >> 4;
    const int R0 = blockIdx.y * 128;
    const int C0 = blockIdx.x * 128;

    f32x4 acc[4][4];
    #pragma unroll
    for (int fa = 0; fa < 4; ++fa)
        #pragma unroll
        for (int fb = 0; fb < 4; ++fb)
            acc[fa][fb] = (f32x4){0.f, 0.f, 0.f, 0.f};

    #pragma unroll 1
    for (int ch = 0; ch < 4; ++ch) {
        const int k0g = ch * 64;
        __syncthreads();
        #pragma unroll
        for (int it = 0; it < 4; ++it) {
            const int lin = tid + it * 256;
            const int row = lin >> 3, f = lin & 7;
            const int kq = f ^ (row & 7);
            gload_lds16b(&Ab[(size_t)(R0 + row) * 256 + k0g + kq * 8],
                         (char*)stA + lin * 16);
            gload_lds16b(&Wb[(size_t)(C0 + row) * 256 + k0g + kq * 8],
                         (char*)stB + lin * 16);
        }
        __syncthreads();

        #pragma unroll
        for (int k0 = 0; k0 < 64; k0 += 32) {
            const int ub = (k0 >> 3) + g;
            bf16x8 af[4], bf[4];
            #pragma unroll
            for (int fb = 0; fb < 4; ++fb) {
                const int jr = wj*64 + fb*16 + l15;
                const int ir = wi*64 + fb*16 + l15;
                af[fb] = *(const bf16x8*)((char*)stB + jr*128 + ((ub ^ (jr & 7)) * 16));
                bf[fb] = *(const bf16x8*)((char*)stA + ir*128 + ((ub ^ (ir & 7)) * 16));
            }
            #pragma unroll
            for (int fa = 0; fa < 4; ++fa)
                #pragma unroll
                for (int fb = 0; fb < 4; ++fb)
                    acc[fa][fb] = __builtin_amdgcn_mfma_f32_16x16x32_bf16(
                        af[fa], bf[fb], acc[fa][fb], 0, 0, 0);
        }
    }

    #pragma unroll
    for (int fa = 0; fa < 4; ++fa)
        #pragma unroll
        for (int fb = 0; fb < 4; ++fb) {
            const int i_ = wi*64 + fb*16 + l15;
            const int j0 = wj*64 + fa*16 + g*4;
            *(f32x4*)&D[i_ * 132 + j0] = acc[fa][fb];
        }
    __syncthreads();

    #pragma unroll
    for (int it = 0; it < 16; ++it) {
        const int linear = it * 256 + tid;
        const int r = linear >> 5, c4 = linear & 31;
        float4 v = *(const float4*)&D[r * 132 + c4 * 4];
        const float s = ROWSCALE ? rscale[R0 + r] : 1.0f;
        float o[4] = {v.x * s, v.y * s, v.z * s, v.w * s};
        #pragma unroll
        for (int cc = 0; cc < 4; ++cc) {
            if (BIAS) o[cc] += bias[C0 + c4*4 + cc];
            if (RELU) o[cc] = fmaxf(o[cc], 0.0f);
        }
        if (F32OUT) {
            *(float4*)&C[(size_t)(R0 + r) * NO + C0 + c4*4] =
                make_float4(o[0], o[1], o[2], o[3]);
        } else {
            ushort4 bv;
            bv.x = f2bf(o[0]); bv.y = f2bf(o[1]);
            bv.z = f2bf(o[2]); bv.w = f2bf(o[3]);
            *(ushort4*)&Cb[(size_t)(R0 + r) * NO + C0 + c4*4] = bv;
        }
    }
}

// ======================================================================
// Row squared-norms
// ======================================================================
__global__ __launch_bounds__(256)
void sq_kernel(const float* __restrict__ h0, float* __restrict__ sq)
{
    const int wid = threadIdx.x >> 6, lane = threadIdx.x & 63;
    const int row = blockIdx.x * 4 + wid;
    float4 v = *(const float4*)&h0[(size_t)row * DIM + lane * 4];
    float s = v.x*v.x + v.y*v.y + v.z*v.z + v.w*v.w;
    #pragma unroll
    for (int o = 32; o > 0; o >>= 1) s += __shfl_down(s, o);
    if (lane == 0) sq[row] = s;
}

// ======================================================================
// Packed-key top-16 insert: sorted-ascending bubble pass, u32 min/max
// ======================================================================
__device__ __forceinline__ void key_insert(unsigned (&kl)[16], unsigned k)
{
    #pragma unroll
    for (int p = 0; p < 16; ++p) {
        const unsigned lo = min(kl[p], k);
        k = max(kl[p], k);
        kl[p] = lo;
    }
}

// ======================================================================
// kNN approx pass: bf16 MFMA 128x128 Gram tiles, packed-key top-16.
// D split into FOUR 32-col phases (D = [128][36] f32 = 18.4 KB, aliased
// under the 32 KB staging) -> LDS_Block_Size 32768 -> 5 blocks/CU
// (residency is the binding constraint; round-11 lesson).
// ======================================================================
__global__ __launch_bounds__(256, 3)
void knn_topk(const unsigned short* __restrict__ h0b, const float* __restrict__ sq,
              unsigned* __restrict__ cand)
{
    __shared__ __align__(16) float smem[8192];   // 32 KB exactly
    char* sbase = (char*)smem;
    unsigned short* stA = (unsigned short*)sbase;            // i rows, bf16[128][64]
    unsigned short* stB = (unsigned short*)(sbase + 16384);  // j rows, bf16[128][64]
    float* D = smem;                                         // f32 [128 i][36]

    const int tid  = threadIdx.x;
    const int lane = tid & 63;
    const int wave = tid >> 6;
    const int wj = wave >> 1;
    const int wi = wave & 1;
    const int l15 = lane & 15;
    const int g   = lane >> 4;
    const int R0 = blockIdx.y * 128;
    const int seg = blockIdx.x;

    const int orow  = tid >> 1;
    const int ohalf = tid & 1;
    const int myrow = R0 + orow;
    const float osq = sq[myrow];

    unsigned kl[16];
    #pragma unroll
    for (int e = 0; e < 16; ++e) kl[e] = 0xFFFFFFFFu;

    for (int jt = 0; jt < JT_PER; ++jt) {
        const int C0 = seg * (NN / SEG) + jt * 128;
        const bool diag = (C0 == R0);          // wave-uniform
        f32x4 acc[4][4];
        #pragma unroll
        for (int fa = 0; fa < 4; ++fa)
            #pragma unroll
            for (int fb = 0; fb < 4; ++fb)
                acc[fa][fb] = (f32x4){0.f, 0.f, 0.f, 0.f};

        #pragma unroll 1
        for (int ch = 0; ch < 4; ++ch) {
            const int k0g = ch * 64;
            __syncthreads();
            #pragma unroll
            for (int it = 0; it < 4; ++it) {
                const int lin = tid + it * 256;
                const int row = lin >> 3, f = lin & 7;
                const int kq = f ^ (row & 7);
                gload_lds16b(&h0b[(size_t)(R0 + row) * DIM + k0g + kq * 8],
                             (char*)stA + lin * 16);
                gload_lds16b(&h0b[(size_t)(C0 + row) * DIM + k0g + kq * 8],
                             (char*)stB + lin * 16);
            }
            __syncthreads();

            #pragma unroll
            for (int k0 = 0; k0 < 64; k0 += 32) {
                const int ub = (k0 >> 3) + g;
                bf16x8 af[4], bf[4];
                #pragma unroll
                for (int fb = 0; fb < 4; ++fb) {
                    const int jr = wj*64 + fb*16 + l15;
                    const int ir = wi*64 + fb*16 + l15;
                    af[fb] = *(const bf16x8*)((char*)stB + jr*128 + ((ub ^ (jr & 7)) * 16));
                    bf[fb] = *(const bf16x8*)((char*)stA + ir*128 + ((ub ^ (ir & 7)) * 16));
                }
                #pragma unroll
                for (int fa = 0; fa < 4; ++fa)
                    #pragma unroll
                    for (int fb = 0; fb < 4; ++fb)
                        acc[fa][fb] = __builtin_amdgcn_mfma_f32_16x16x32_bf16(
                            af[fa], bf[fb], acc[fa][fb], 0, 0, 0);
            }
        }

        // four 32-col dump/scan phases (D = [128][36] f32, aliases staging)
        #pragma unroll 1
        for (int p = 0; p < 4; ++p) {
            __syncthreads();   // frag reads (p=0) / prior scan done
            if (wj == (p >> 1)) {
                const int fab = 2 * (p & 1);
                #pragma unroll
                for (int fl = 0; fl < 2; ++fl)
                    #pragma unroll
                    for (int fb = 0; fb < 4; ++fb) {
                        const int i_ = wi*64 + fb*16 + l15;
                        *(f32x4*)&D[i_ * 36 + fl*16 + g*4] = acc[fab + fl][fb];
                    }
            }
            __syncthreads();

            const int cb = C0 + p*32 + ohalf*16;
            const float* Dr = &D[orow * 36 + ohalf * 16];
            #pragma clang loop unroll(disable)
            for (int e = 0; e < 4; ++e) {
                const float4 dv4 = *(const float4*)&Dr[e * 4];
                const float4 sv4 = *(const float4*)&sq[cb + e * 4];
                const int j0 = cb + e * 4;
                unsigned k0 = pack_key((osq + sv4.x) - 2.0f * dv4.x, j0 + 0);
                unsigned k1 = pack_key((osq + sv4.y) - 2.0f * dv4.y, j0 + 1);
                unsigned k2 = pack_key((osq + sv4.z) - 2.0f * dv4.z, j0 + 2);
                unsigned k3 = pack_key((osq + sv4.w) - 2.0f * dv4.w, j0 + 3);
                if (diag) {
                    if (j0 + 0 == myrow) k0 = 0xFFFFFFFFu;
                    if (j0 + 1 == myrow) k1 = 0xFFFFFFFFu;
                    if (j0 + 2 == myrow) k2 = 0xFFFFFFFFu;
                    if (j0 + 3 == myrow) k3 = 0xFFFFFFFFu;
                }
                const unsigned kmin = min(min(k0, k1), min(k2, k3));
                if (kmin < kl[15]) {
                    if (k0 < kl[15]) key_insert(kl, k0);
                    if (k1 < kl[15]) key_insert(kl, k1);
                    if (k2 < kl[15]) key_insert(kl, k2);
                    if (k3 < kl[15]) key_insert(kl, k3);
                }
            }
        }
    }

    // block-level merge: 2 sorted half-lists per row -> sorted 16 per (seg,row)
    __syncthreads();
    unsigned* ck = (unsigned*)smem;     // [256][17] u32 = 17.4 KB <= 32 KB
    #pragma unroll
    for (int e = 0; e < 16; ++e) ck[tid * 17 + e] = kl[e];
    __syncthreads();
    if (tid < 128) {
        const unsigned* LA = &ck[(2*tid) * 17];
        const unsigned* LB = &ck[(2*tid + 1) * 17];
        int pa = 0, pb = 0;
        const size_t obase = ((size_t)seg * NN + R0 + tid) * 16;
        #pragma clang loop unroll(disable)
        for (int r = 0; r < 16; ++r) {
            const unsigned ka = LA[pa], kb = LB[pb];
            const bool takeA = (ka < kb);
            cand[obase + r] = takeA ? ka : kb;
            if (takeA) ++pa; else ++pb;
        }
    }
}

// ======================================================================
// Fused select: 8-way merge (register-resident, no LDS) -> top-32
// candidates -> exact fp32 refine -> nbr + indeg atomics.
// 8 rows per 256-block, 32 lanes per row (merge runs in 4 duplicate
// aligned 8-lane clusters; lane `sub` captures winner #sub).
// ======================================================================
__global__ __launch_bounds__(256)
void select_k(const unsigned* __restrict__ cand, const float* __restrict__ h0,
              const float* __restrict__ sq, int* __restrict__ nbr,
              int* __restrict__ indeg)
{
    const int tid = threadIdx.x;
    const int sub = tid & 31;
    const int row = blockIdx.x * 8 + (tid >> 5);

    // phase 1: merge 8 sorted seg lists; lane sub keeps the sub-th winner
    int myj = 0;
    {
        const int l8 = sub & 7;
        const size_t base = ((size_t)l8 * NN + row) * 16;
        int head = 0;
        #pragma clang loop unroll(disable)
        for (int r = 0; r < 32; ++r) {
            unsigned mk = (head < 16) ? cand[base + head] : 0xFFFFFFFFu;
            int ml = l8;
            #pragma unroll
            for (int off = 1; off < 8; off <<= 1) {
                const unsigned ok = __shfl_xor(mk, off);
                const int      ol = __shfl_xor(ml, off);
                if (ok < mk) { mk = ok; ml = ol; }
            }
            if (r == sub) myj = (int)(mk & 0x3FFFu);
            if (ml == l8) ++head;
        }
    }

    // phase 2: exact fp32 distance for this lane's candidate
    const int j = myj;
    float dot = 0.0f;
    #pragma clang loop unroll_count(4)
    for (int k = 0; k < DIM; k += 4) {
        float4 a = *(const float4*)&h0[(size_t)row * DIM + k];
        float4 b = *(const float4*)&h0[(size_t)j * DIM + k];
        dot += a.x*b.x + a.y*b.y + a.z*b.z + a.w*b.w;
    }
    float d = sq[row] + sq[j] - 2.0f * dot;

    // phase 3: 16 knockout rounds -> nbr + indeg
    const int ji = j;
    for (int t = 0; t < 16; ++t) {
        float md = d; int mi = ji;
        #pragma unroll
        for (int off = 1; off < 32; off <<= 1) {
            const float od = __shfl_xor(md, off);
            const int   oi = __shfl_xor(mi, off);
            if (od < md || (od == md && oi < mi)) { md = od; mi = oi; }
        }
        if (d == md && ji == mi) d = 3e38f;
        if (sub == 0) {
            nbr[(size_t)row * KNN + t] = mi;
            atomicAdd(&indeg[mi], 1);
        }
    }
}

// ======================================================================
// Graph build
// ======================================================================
__global__ __launch_bounds__(1024)
void scan_k(const int* __restrict__ indeg, int* __restrict__ offs,
            float* __restrict__ dinv)
{
    __shared__ int part[1024];
    const int t = threadIdx.x;
    int pre[16]; int s = 0;
    #pragma unroll
    for (int j = 0; j < 16; ++j) { pre[j] = s; s += indeg[t*16 + j]; }
    part[t] = s;
    __syncthreads();
    for (int d = 1; d < 1024; d <<= 1) {
        int v = (t >= d) ? part[t - d] : 0;
        __syncthreads();
        part[t] += v;
        __syncthreads();
    }
    const int base = (t > 0) ? part[t-1] : 0;
    #pragma unroll
    for (int j = 0; j < 16; ++j) {
        offs[t*16 + j] = base + pre[j];
        dinv[t*16 + j] = rsqrtf((float)(indeg[t*16 + j] + KNN + 1));
    }
}

__global__ void fill_k(const int* __restrict__ nbr, const int* __restrict__ offs,
                       int* __restrict__ cursor, int* __restrict__ rev)
{
    const int e = blockIdx.x * 256 + threadIdx.x;
    const int v = nbr[e];
    const int i = e >> 4;
    const int p = atomicAdd(&cursor[v], 1);
    rev[offs[v] + p] = i;
}

// ======================================================================
// GCN aggregation, bf16 in / bf16 out. ONE VERTEX PER BLOCK:
// 32 feature-lanes x 8 degree-parallel groups, fixed-order LDS reduce.
// ======================================================================
__device__ __forceinline__ void acc_row8(float (&acc)[8], const unsigned short* p)
{
    const uint4 u = *(const uint4*)p;
    acc[0] += __uint_as_float(u.x << 16);
    acc[1] += __uint_as_float(u.x & 0xffff0000u);
    acc[2] += __uint_as_float(u.y << 16);
    acc[3] += __uint_as_float(u.y & 0xffff0000u);
    acc[4] += __uint_as_float(u.z << 16);
    acc[5] += __uint_as_float(u.z & 0xffff0000u);
    acc[6] += __uint_as_float(u.w << 16);
    acc[7] += __uint_as_float(u.w & 0xffff0000u);
}

__global__ __launch_bounds__(256)
void gatherv_k(const unsigned short* __restrict__ mb, const int* __restrict__ nbr,
               const int* __restrict__ rev, const int* __restrict__ offs,
               const int* __restrict__ indeg, const float* __restrict__ dinv,
               const float* __restrict__ bias, unsigned short* __restrict__ outb)
{
    __shared__ float red[8][256];
    const int v   = blockIdx.x;
    const int tid = threadIdx.x;
    const int grp = tid >> 5;
    const int sub = tid & 31;
    const int f0  = sub * 8;

    float acc[8] = {};
    #pragma clang loop unroll(disable)
    for (int t = grp; t < 17; t += 8) {
        const int u = (t == 16) ? v : nbr[(size_t)v * KNN + t];
        acc_row8(acc, &mb[(size_t)u * DIM + f0]);
    }
    const int o = offs[v], n = indeg[v];
    #pragma clang loop unroll_count(2)
    for (int t = grp; t < n; t += 8) {
        acc_row8(acc, &mb[(size_t)rev[o + t] * DIM + f0]);
    }

    #pragma unroll
    for (int e = 0; e < 8; ++e) red[grp][f0 + e] = acc[e];
    __syncthreads();

    float s = 0.0f;
    #pragma unroll
    for (int g2 = 0; g2 < 8; ++g2) s += red[g2][tid];
    const float r = dinv[v] * s + bias[tid];
    outb[(size_t)v * DIM + tid] = f2bf(fmaxf(r, 0.0f));
}

// ======================================================================
// FC2: coalesced, 8 rows per 256-block, shfl-reduce over 32 lanes
// ======================================================================
__global__ __launch_bounds__(256)
void fc2_k(const float* __restrict__ hid, const float* __restrict__ W,
           const float* __restrict__ b, float* __restrict__ out)
{
    __shared__ float Ws[1280];
    __shared__ float bs[16];
    const int tid = threadIdx.x;
    for (int i = tid; i < 1280; i += 256) Ws[i] = W[i];
    if (tid < 10) bs[tid] = b[tid];
    __syncthreads();
    const int row = blockIdx.x * 8 + (tid >> 5);
    const int sub = tid & 31;
    float4 h4 = *(const float4*)&hid[(size_t)row * 128 + sub * 4];
    float a[10];
    #pragma unroll
    for (int c = 0; c < 10; ++c) {
        float4 w4 = *(const float4*)&Ws[c * 128 + sub * 4];
        a[c] = h4.x*w4.x + h4.y*w4.y + h4.z*w4.z + h4.w*w4.w;
    }
    #pragma unroll
    for (int off = 16; off >= 1; off >>= 1)
        #pragma unroll
        for (int c = 0; c < 10; ++c) a[c] += __shfl_down(a[c], off, 32);
    if (sub == 0) {
        #pragma unroll
        for (int c = 0; c < 10; ++c) out[(size_t)row * 10 + c] = a[c] + bs[c];
    }
}

// ======================================================================
extern "C" void kernel_launch(void* const* d_in, const int* in_sizes, int n_in,
                              void* d_out, int out_size, void* d_ws, size_t ws_size,
                              hipStream_t stream)
{
    const float* x     = (const float*)d_in[0];
    const float* Wpre  = (const float*)d_in[1];
    const float* bpre  = (const float*)d_in[2];
    const float* Wconv = (const float*)d_in[3];   // [2][256][256]
    const float* bconv = (const float*)d_in[4];   // [2][256]
    const float* Wfc1  = (const float*)d_in[5];   // [128][256]
    const float* bfc1  = (const float*)d_in[6];
    const float* Wfc2  = (const float*)d_in[7];   // [10][128]
    const float* bfc2  = (const float*)d_in[8];
    float* out = (float*)d_out;

    float* ws    = (float*)d_ws;
    float* h0    = ws;                               // NN*DIM f32 (later m2b bf16)
    float* mbuf  = h0    + (size_t)NN*DIM;           // NN*DIM  (xh/xl early, m1b later)
    float* hfbuf = mbuf  + (size_t)NN*DIM;           // NN*DIM  (cand early, hf_b/hf2_b later)
    float* hid   = hfbuf + (size_t)NN*DIM;           // NN*128  (h0b early, hid late)
    float* sqv   = hid   + (size_t)NN*128;           // NN
    float* dinv  = sqv   + NN;                       // NN
    int*   nbr   = (int*)(dinv + NN);                // NN*KNN
    int*   indeg = nbr   + (size_t)NN*KNN;           // NN
    int*   offs  = indeg + NN;                       // NN
    int*   cursor= offs  + NN;                       // NN
    int*   rev   = cursor+ NN;                       // NN*KNN
    unsigned short* wbc  = (unsigned short*)(rev + (size_t)NN*KNN);  // 2*256*256 bf16
    unsigned short* wbf1 = wbc + 2*256*256;                          // 128*256 bf16
    unsigned short* wph  = wbf1 + 128*256;                           // 256*256 bf16
    unsigned short* wpl  = wph + 256*256;                            // 256*256 bf16

    // aliases (stream-ordered safe):
    unsigned short* h0b   = (unsigned short*)hid;        // bf16(h0), dead before FC1 writes hid
    unsigned short* xh    = (unsigned short*)mbuf;       // x hi, dead after pre_mfma
    unsigned short* xl    = xh + (size_t)NN*DIM;         // x lo, dead after pre_mfma
    unsigned* cand  = (unsigned*)hfbuf;                  // SEG*NN*16 u32 (8 MB), dead after select
    unsigned short* m1b   = (unsigned short*)mbuf;       // bf16 messages L1
    unsigned short* m2b   = (unsigned short*)h0;         // bf16 messages L2 (h0 dead after select)
    unsigned short* hf_b  = (unsigned short*)hfbuf;                      // bf16 hf
    unsigned short* hf2_b = (unsigned short*)(hfbuf + (size_t)NN*DIM/2); // bf16 hf2

    hipMemsetAsync(indeg,  0, NN*sizeof(int), stream);
    hipMemsetAsync(cursor, 0, NN*sizeof(int), stream);

    // 0. conversions
    convert_hilo_k<<<NN*DIM/1024, 256, 0, stream>>>(x, xh, xl);
    convert_hilo_k<<<DIM*DIM/1024, 256, 0, stream>>>(Wpre, wph, wpl);
    convert_bf16_k<<<2*256*256/1024, 256, 0, stream>>>(Wconv, wbc);
    convert_bf16_k<<<128*256/1024,   256, 0, stream>>>(Wfc1, wbf1);

    // 1. h0 = relu(x @ Wpre^T + bpre) via split-bf16 MFMA + bf16 shadow
    pre_mfma<<<dim3(DIM/128, NN/128), 256, 0, stream>>>(
        xh, xl, wph, wpl, bpre, h0, h0b);
    // 2. row squared norms
    sq_kernel<<<NN/4, 256, 0, stream>>>(h0, sqv);
    // 3. approx 16-NN (bf16 MFMA, packed keys) -> per-seg top-16
    knn_topk<<<dim3(SEG, NN/128), 256, 0, stream>>>(h0b, sqv, cand);
    // 3b. fused merge -> refine -> nbr + indeg
    select_k<<<NN/8, 256, 0, stream>>>(cand, h0, sqv, nbr, indeg);
    // 4. graph build
    scan_k<<<1, 1024, 0, stream>>>(indeg, offs, dinv);
    fill_k<<<NN*KNN/256, 256, 0, stream>>>(nbr, offs, cursor, rev);
    // 5. GCN layer 1: m1b = bf16(dinv*(h0b @ Wc0^T)); gather -> hf_b
    gemm_mfma<false,false,true,false><<<dim3(DIM/128, NN/128), 256, 0, stream>>>(
        h0b, wbc, nullptr, dinv, nullptr, m1b, DIM);
    gatherv_k<<<NN, 256, 0, stream>>>(m1b, nbr, rev, offs, indeg, dinv, bconv, hf_b);
    // 6. GCN layer 2: m2b = bf16(dinv*(hf_b @ Wc1^T)); gather -> hf2_b
    gemm_mfma<false,false,true,false><<<dim3(DIM/128, NN/128), 256, 0, stream>>>(
        hf_b, wbc + 256*256, nullptr, dinv, nullptr, m2b, DIM);
    gatherv_k<<<NN, 256, 0, stream>>>(m2b, nbr, rev, offs, indeg, dinv, bconv + DIM, hf2_b);
    // 7. FC1: hid = relu(hf2_b @ Wfc1^T + b) f32
    gemm_mfma<true,true,false,true><<<dim3(128/128, NN/128), 256, 0, stream>>>(
        hf2_b, wbf1, bfc1, nullptr, hid, nullptr, 128);
    // 8. FC2
    fc2_k<<<NN/8, 256, 0, stream>>>(hid, Wfc2, bfc2, out);
}

// Round 14
// 817.246 us; speedup vs baseline: 1.7370x; 1.7370x over previous
//
#include <hip/hip_runtime.h>

#define NN   16384
#define DIM  256
#define KNN  16
#define SEG  8
#define JT_PER (NN / SEG / 128)   // 16 column tiles per segment

typedef __attribute__((ext_vector_type(8))) short  bf16x8;
typedef __attribute__((ext_vector_type(4))) float  f32x4;

// ======================================================================
// async global->LDS 16B helper (linear LDS dest, per-lane global source)
// ======================================================================
__device__ __forceinline__ void gload_lds16b(const unsigned short* g, void* l)
{
    __builtin_amdgcn_global_load_lds(
        (const __attribute__((address_space(1))) unsigned int*)g,
        (__attribute__((address_space(3))) unsigned int*)l, 16, 0, 0);
}

// float -> bf16 (RNE, finite inputs)
__device__ __forceinline__ unsigned short f2bf(float x)
{
    unsigned int u = __float_as_uint(x);
    unsigned int r = (u + 0x7fffu + ((u >> 16) & 1u)) >> 16;
    return (unsigned short)r;
}
__device__ __forceinline__ float bf2f(unsigned short u)
{
    return __uint_as_float(((unsigned)u) << 16);
}

// pack (distance, col) into one sortable u32: 18 d-bits | 14 j-bits
__device__ __forceinline__ unsigned pack_key(float d, int j)
{
    return (__float_as_uint(fmaxf(d, 0.0f)) & 0xFFFFC000u) | (unsigned)j;
}

// ======================================================================
// fp32 -> bf16 convert
// ======================================================================
__global__ __launch_bounds__(256)
void convert_bf16_k(const float* __restrict__ in, unsigned short* __restrict__ out)
{
    const int i4 = blockIdx.x * 256 + threadIdx.x;
    float4 v = *(const float4*)&in[(size_t)i4 * 4];
    ushort4 b;
    b.x = f2bf(v.x); b.y = f2bf(v.y); b.z = f2bf(v.z); b.w = f2bf(v.w);
    *(ushort4*)&out[(size_t)i4 * 4] = b;
}

// fp32 -> (hi, lo) bf16 split: v ~= hi + lo
__global__ __launch_bounds__(256)
void convert_hilo_k(const float* __restrict__ in,
                    unsigned short* __restrict__ hi, unsigned short* __restrict__ lo)
{
    const int i4 = blockIdx.x * 256 + threadIdx.x;
    float4 v = *(const float4*)&in[(size_t)i4 * 4];
    ushort4 h, l;
    h.x = f2bf(v.x); l.x = f2bf(v.x - bf2f(h.x));
    h.y = f2bf(v.y); l.y = f2bf(v.y - bf2f(h.y));
    h.z = f2bf(v.z); l.z = f2bf(v.z - bf2f(h.z));
    h.w = f2bf(v.w); l.w = f2bf(v.w - bf2f(h.w));
    *(ushort4*)&hi[(size_t)i4 * 4] = h;
    *(ushort4*)&lo[(size_t)i4 * 4] = l;
}

// ======================================================================
// Split-bf16 MFMA pre-GEMM:  h0 = relu( (xh+xl) @ (Wh+Wl)^T + b )
// = xh*Wh + xl*Wh + xh*Wl.  Emits f32 h0 + bf16 shadow.
// ======================================================================
__global__ __launch_bounds__(256, 1)
void pre_mfma(const unsigned short* __restrict__ xh, const unsigned short* __restrict__ xl,
              const unsigned short* __restrict__ wh, const unsigned short* __restrict__ wl,
              const float* __restrict__ bias,
              float* __restrict__ C, unsigned short* __restrict__ Cb)
{
    __shared__ __align__(16) float smem[16896];              // 67.6 KB
    unsigned short* stAh = (unsigned short*)smem;
    unsigned short* stAl = (unsigned short*)((char*)smem + 16384);
    unsigned short* stBh = (unsigned short*)((char*)smem + 32768);
    unsigned short* stBl = (unsigned short*)((char*)smem + 49152);
    float* D = smem;                                         // f32 [128][132]

    const int tid  = threadIdx.x;
    const int lane = tid & 63;
    const int wave = tid >> 6;
    const int wj = wave >> 1;
    const int wi = wave & 1;
    const int l15 = lane & 15;
    const int g   = lane >> 4;
    const int R0 = blockIdx.y * 128;
    const int C0 = blockIdx.x * 128;

    f32x4 acc[4][4];
    #pragma unroll
    for (int fa = 0; fa < 4; ++fa)
        #pragma unroll
        for (int fb = 0; fb < 4; ++fb)
            acc[fa][fb] = (f32x4){0.f, 0.f, 0.f, 0.f};

    #pragma unroll 1
    for (int ch = 0; ch < 4; ++ch) {
        const int k0g = ch * 64;
        __syncthreads();
        #pragma unroll
        for (int it = 0; it < 4; ++it) {
            const int lin = tid + it * 256;
            const int row = lin >> 3, f = lin & 7;
            const int kq = f ^ (row & 7);
            gload_lds16b(&xh[(size_t)(R0 + row) * 256 + k0g + kq * 8], (char*)stAh + lin * 16);
            gload_lds16b(&xl[(size_t)(R0 + row) * 256 + k0g + kq * 8], (char*)stAl + lin * 16);
            gload_lds16b(&wh[(size_t)(C0 + row) * 256 + k0g + kq * 8], (char*)stBh + lin * 16);
            gload_lds16b(&wl[(size_t)(C0 + row) * 256 + k0g + kq * 8], (char*)stBl + lin * 16);
        }
        __syncthreads();

        #pragma unroll
        for (int k0 = 0; k0 < 64; k0 += 32) {
            const int ub = (k0 >> 3) + g;
            bf16x8 afh[4], afl[4], bfh[4], bfl[4];
            #pragma unroll
            for (int q = 0; q < 4; ++q) {
                const int jr = wj*64 + q*16 + l15;
                const int ir = wi*64 + q*16 + l15;
                const int oj = (ub ^ (jr & 7)) * 16;
                const int oi = (ub ^ (ir & 7)) * 16;
                afh[q] = *(const bf16x8*)((char*)stBh + jr*128 + oj);
                afl[q] = *(const bf16x8*)((char*)stBl + jr*128 + oj);
                bfh[q] = *(const bf16x8*)((char*)stAh + ir*128 + oi);
                bfl[q] = *(const bf16x8*)((char*)stAl + ir*128 + oi);
            }
            #pragma unroll
            for (int fa = 0; fa < 4; ++fa)
                #pragma unroll
                for (int fb = 0; fb < 4; ++fb) {
                    acc[fa][fb] = __builtin_amdgcn_mfma_f32_16x16x32_bf16(
                        afh[fa], bfl[fb], acc[fa][fb], 0, 0, 0);
                    acc[fa][fb] = __builtin_amdgcn_mfma_f32_16x16x32_bf16(
                        afl[fa], bfh[fb], acc[fa][fb], 0, 0, 0);
                    acc[fa][fb] = __builtin_amdgcn_mfma_f32_16x16x32_bf16(
                        afh[fa], bfh[fb], acc[fa][fb], 0, 0, 0);
                }
        }
    }

    __syncthreads();
    #pragma unroll
    for (int fa = 0; fa < 4; ++fa)
        #pragma unroll
        for (int fb = 0; fb < 4; ++fb) {
            const int i_ = wi*64 + fb*16 + l15;
            const int j0 = wj*64 + fa*16 + g*4;
            *(f32x4*)&D[i_ * 132 + j0] = acc[fa][fb];
        }
    __syncthreads();

    #pragma unroll
    for (int it = 0; it < 16; ++it) {
        const int linear = it * 256 + tid;
        const int r = linear >> 5, c4 = linear & 31;
        float4 v = *(const float4*)&D[r * 132 + c4 * 4];
        float o[4] = {v.x, v.y, v.z, v.w};
        #pragma unroll
        for (int cc = 0; cc < 4; ++cc) {
            o[cc] += bias[C0 + c4*4 + cc];
            o[cc] = fmaxf(o[cc], 0.0f);
        }
        *(float4*)&C[(size_t)(R0 + r) * 256 + C0 + c4*4] =
            make_float4(o[0], o[1], o[2], o[3]);
        ushort4 bv;
        bv.x = f2bf(o[0]); bv.y = f2bf(o[1]);
        bv.z = f2bf(o[2]); bv.w = f2bf(o[3]);
        *(ushort4*)&Cb[(size_t)(R0 + r) * 256 + C0 + c4*4] = bv;
    }
}

// ======================================================================
// bf16-MFMA GEMM: out = act( rowscale*(Ab @ Wb^T) + bias ), K = 256.
// ======================================================================
template<bool RELU, bool BIAS, bool ROWSCALE, bool F32OUT>
__global__ __launch_bounds__(256, 1)
void gemm_mfma(const unsigned short* __restrict__ Ab, const unsigned short* __restrict__ Wb,
               const float* __restrict__ bias, const float* __restrict__ rscale,
               float* __restrict__ C, unsigned short* __restrict__ Cb, int NO)
{
    __shared__ __align__(16) float smem[25088];            // 98 KB
    unsigned short* stA = (unsigned short*)smem;
    unsigned short* stB = (unsigned short*)(smem + 4096);
    float* D = smem + 8192;

    const int tid  = threadIdx.x;
    const int lane = tid & 63;
    const int wave = tid >> 6;
    const int wj = wave >> 1;
    const int wi = wave & 1;
    const int l15 = lane & 15;
    const int g   = lane >> 4;
    const int R0 = blockIdx.y * 128;
    const int C0 = blockIdx.x * 128;

    f32x4 acc[4][4];
    #pragma unroll
    for (int fa = 0; fa < 4; ++fa)
        #pragma unroll
        for (int fb = 0; fb < 4; ++fb)
            acc[fa][fb] = (f32x4){0.f, 0.f, 0.f, 0.f};

    #pragma unroll 1
    for (int ch = 0; ch < 4; ++ch) {
        const int k0g = ch * 64;
        __syncthreads();
        #pragma unroll
        for (int it = 0; it < 4; ++it) {
            const int lin = tid + it * 256;
            const int row = lin >> 3, f = lin & 7;
            const int kq = f ^ (row & 7);
            gload_lds16b(&Ab[(size_t)(R0 + row) * 256 + k0g + kq * 8],
                         (char*)stA + lin * 16);
            gload_lds16b(&Wb[(size_t)(C0 + row) * 256 + k0g + kq * 8],
                         (char*)stB + lin * 16);
        }
        __syncthreads();

        #pragma unroll
        for (int k0 = 0; k0 < 64; k0 += 32) {
            const int ub = (k0 >> 3) + g;
            bf16x8 af[4], bf[4];
            #pragma unroll
            for (int fb = 0; fb < 4; ++fb) {
                const int jr = wj*64 + fb*16 + l15;
                const int ir = wi*64 + fb*16 + l15;
                af[fb] = *(const bf16x8*)((char*)stB + jr*128 + ((ub ^ (jr & 7)) * 16));
                bf[fb] = *(const bf16x8*)((char*)stA + ir*128 + ((ub ^ (ir & 7)) * 16));
            }
            #pragma unroll
            for (int fa = 0; fa < 4; ++fa)
                #pragma unroll
                for (int fb = 0; fb < 4; ++fb)
                    acc[fa][fb] = __builtin_amdgcn_mfma_f32_16x16x32_bf16(
                        af[fa], bf[fb], acc[fa][fb], 0, 0, 0);
        }
    }

    #pragma unroll
    for (int fa = 0; fa < 4; ++fa)
        #pragma unroll
        for (int fb = 0; fb < 4; ++fb) {
            const int i_ = wi*64 + fb*16 + l15;
            const int j0 = wj*64 + fa*16 + g*4;
            *(f32x4*)&D[i_ * 132 + j0] = acc[fa][fb];
        }
    __syncthreads();

    #pragma unroll
    for (int it = 0; it < 16; ++it) {
        const int linear = it * 256 + tid;
        const int r = linear >> 5, c4 = linear & 31;
        float4 v = *(const float4*)&D[r * 132 + c4 * 4];
        const float s = ROWSCALE ? rscale[R0 + r] : 1.0f;
        float o[4] = {v.x * s, v.y * s, v.z * s, v.w * s};
        #pragma unroll
        for (int cc = 0; cc < 4; ++cc) {
            if (BIAS) o[cc] += bias[C0 + c4*4 + cc];
            if (RELU) o[cc] = fmaxf(o[cc], 0.0f);
        }
        if (F32OUT) {
            *(float4*)&C[(size_t)(R0 + r) * NO + C0 + c4*4] =
                make_float4(o[0], o[1], o[2], o[3]);
        } else {
            ushort4 bv;
            bv.x = f2bf(o[0]); bv.y = f2bf(o[1]);
            bv.z = f2bf(o[2]); bv.w = f2bf(o[3]);
            *(ushort4*)&Cb[(size_t)(R0 + r) * NO + C0 + c4*4] = bv;
        }
    }
}

// ======================================================================
// Row squared-norms
// ======================================================================
__global__ __launch_bounds__(256)
void sq_kernel(const float* __restrict__ h0, float* __restrict__ sq)
{
    const int wid = threadIdx.x >> 6, lane = threadIdx.x & 63;
    const int row = blockIdx.x * 4 + wid;
    float4 v = *(const float4*)&h0[(size_t)row * DIM + lane * 4];
    float s = v.x*v.x + v.y*v.y + v.z*v.z + v.w*v.w;
    #pragma unroll
    for (int o = 32; o > 0; o >>= 1) s += __shfl_down(s, o);
    if (lane == 0) sq[row] = s;
}

// ======================================================================
// Packed-key top-16 insert: sorted-ascending bubble pass, u32 min/max
// ======================================================================
__device__ __forceinline__ void key_insert(unsigned (&kl)[16], unsigned k)
{
    #pragma unroll
    for (int p = 0; p < 16; ++p) {
        const unsigned lo = min(kl[p], k);
        k = max(kl[p], k);
        kl[p] = lo;
    }
}

// ======================================================================
// kNN approx pass: bf16 MFMA 128x128 Gram tiles, packed-key top-16.
// D in FOUR 32-col phases (D = [128][36] f32, aliased under the 32 KB
// staging) -> LDS_Block_Size 32768 -> 5 blocks/CU.
// Phase loop FULLY UNROLLED so all acc indices are compile-time
// (round-13 lesson / rule #20: runtime-indexed acc -> scratch -> 4.3 GB
// of spill traffic; WRITE_SIZE is the canary).
// ======================================================================
__global__ __launch_bounds__(256, 3)
void knn_topk(const unsigned short* __restrict__ h0b, const float* __restrict__ sq,
              unsigned* __restrict__ cand)
{
    __shared__ __align__(16) float smem[8192];   // 32 KB exactly
    char* sbase = (char*)smem;
    unsigned short* stA = (unsigned short*)sbase;            // i rows, bf16[128][64]
    unsigned short* stB = (unsigned short*)(sbase + 16384);  // j rows, bf16[128][64]
    float* D = smem;                                         // f32 [128 i][36]

    const int tid  = threadIdx.x;
    const int lane = tid & 63;
    const int wave = tid >> 6;
    const int wj = wave >> 1;
    const int wi = wave & 1;
    const int l15 = lane & 15;
    const int g   = lane >> 4;
    const int R0 = blockIdx.y * 128;
    const int seg = blockIdx.x;

    const int orow  = tid >> 1;
    const int ohalf = tid & 1;
    const int myrow = R0 + orow;
    const float osq = sq[myrow];

    unsigned kl[16];
    #pragma unroll
    for (int e = 0; e < 16; ++e) kl[e] = 0xFFFFFFFFu;

    for (int jt = 0; jt < JT_PER; ++jt) {
        const int C0 = seg * (NN / SEG) + jt * 128;
        const bool diag = (C0 == R0);          // wave-uniform
        f32x4 acc[4][4];
        #pragma unroll
        for (int fa = 0; fa < 4; ++fa)
            #pragma unroll
            for (int fb = 0; fb < 4; ++fb)
                acc[fa][fb] = (f32x4){0.f, 0.f, 0.f, 0.f};

        #pragma unroll 1
        for (int ch = 0; ch < 4; ++ch) {
            const int k0g = ch * 64;
            __syncthreads();
            #pragma unroll
            for (int it = 0; it < 4; ++it) {
                const int lin = tid + it * 256;
                const int row = lin >> 3, f = lin & 7;
                const int kq = f ^ (row & 7);
                gload_lds16b(&h0b[(size_t)(R0 + row) * DIM + k0g + kq * 8],
                             (char*)stA + lin * 16);
                gload_lds16b(&h0b[(size_t)(C0 + row) * DIM + k0g + kq * 8],
                             (char*)stB + lin * 16);
            }
            __syncthreads();

            #pragma unroll
            for (int k0 = 0; k0 < 64; k0 += 32) {
                const int ub = (k0 >> 3) + g;
                bf16x8 af[4], bf[4];
                #pragma unroll
                for (int fb = 0; fb < 4; ++fb) {
                    const int jr = wj*64 + fb*16 + l15;
                    const int ir = wi*64 + fb*16 + l15;
                    af[fb] = *(const bf16x8*)((char*)stB + jr*128 + ((ub ^ (jr & 7)) * 16));
                    bf[fb] = *(const bf16x8*)((char*)stA + ir*128 + ((ub ^ (ir & 7)) * 16));
                }
                #pragma unroll
                for (int fa = 0; fa < 4; ++fa)
                    #pragma unroll
                    for (int fb = 0; fb < 4; ++fb)
                        acc[fa][fb] = __builtin_amdgcn_mfma_f32_16x16x32_bf16(
                            af[fa], bf[fb], acc[fa][fb], 0, 0, 0);
            }
        }

        // four 32-col dump/scan phases, FULLY UNROLLED (static acc indices)
        #pragma unroll
        for (int p = 0; p < 4; ++p) {
            __syncthreads();   // frag reads (p=0) / prior scan done
            if (wj == (p >> 1)) {
                #pragma unroll
                for (int fl = 0; fl < 2; ++fl)
                    #pragma unroll
                    for (int fb = 0; fb < 4; ++fb) {
                        const int i_ = wi*64 + fb*16 + l15;
                        *(f32x4*)&D[i_ * 36 + fl*16 + g*4] = acc[2*(p&1) + fl][fb];
                    }
            }
            __syncthreads();

            const int cb = C0 + p*32 + ohalf*16;
            const float* Dr = &D[orow * 36 + ohalf * 16];
            #pragma clang loop unroll(disable)
            for (int e = 0; e < 4; ++e) {
                const float4 dv4 = *(const float4*)&Dr[e * 4];
                const float4 sv4 = *(const float4*)&sq[cb + e * 4];
                const int j0 = cb + e * 4;
                unsigned k0 = pack_key((osq + sv4.x) - 2.0f * dv4.x, j0 + 0);
                unsigned k1 = pack_key((osq + sv4.y) - 2.0f * dv4.y, j0 + 1);
                unsigned k2 = pack_key((osq + sv4.z) - 2.0f * dv4.z, j0 + 2);
                unsigned k3 = pack_key((osq + sv4.w) - 2.0f * dv4.w, j0 + 3);
                if (diag) {
                    if (j0 + 0 == myrow) k0 = 0xFFFFFFFFu;
                    if (j0 + 1 == myrow) k1 = 0xFFFFFFFFu;
                    if (j0 + 2 == myrow) k2 = 0xFFFFFFFFu;
                    if (j0 + 3 == myrow) k3 = 0xFFFFFFFFu;
                }
                const unsigned kmin = min(min(k0, k1), min(k2, k3));
                if (kmin < kl[15]) {
                    if (k0 < kl[15]) key_insert(kl, k0);
                    if (k1 < kl[15]) key_insert(kl, k1);
                    if (k2 < kl[15]) key_insert(kl, k2);
                    if (k3 < kl[15]) key_insert(kl, k3);
                }
            }
        }
    }

    // block-level merge: 2 sorted half-lists per row -> sorted 16 per (seg,row)
    __syncthreads();
    unsigned* ck = (unsigned*)smem;     // [256][17] u32 = 17.4 KB <= 32 KB
    #pragma unroll
    for (int e = 0; e < 16; ++e) ck[tid * 17 + e] = kl[e];
    __syncthreads();
    if (tid < 128) {
        const unsigned* LA = &ck[(2*tid) * 17];
        const unsigned* LB = &ck[(2*tid + 1) * 17];
        int pa = 0, pb = 0;
        const size_t obase = ((size_t)seg * NN + R0 + tid) * 16;
        #pragma clang loop unroll(disable)
        for (int r = 0; r < 16; ++r) {
            const unsigned ka = LA[pa], kb = LB[pb];
            const bool takeA = (ka < kb);
            cand[obase + r] = takeA ? ka : kb;
            if (takeA) ++pa; else ++pb;
        }
    }
}

// ======================================================================
// Fused select: 8-way merge (register-resident, no LDS) -> top-32
// candidates -> exact fp32 refine -> nbr + indeg atomics.
// ======================================================================
__global__ __launch_bounds__(256)
void select_k(const unsigned* __restrict__ cand, const float* __restrict__ h0,
              const float* __restrict__ sq, int* __restrict__ nbr,
              int* __restrict__ indeg)
{
    const int tid = threadIdx.x;
    const int sub = tid & 31;
    const int row = blockIdx.x * 8 + (tid >> 5);

    // phase 1: merge 8 sorted seg lists; lane sub keeps the sub-th winner
    int myj = 0;
    {
        const int l8 = sub & 7;
        const size_t base = ((size_t)l8 * NN + row) * 16;
        int head = 0;
        #pragma clang loop unroll(disable)
        for (int r = 0; r < 32; ++r) {
            unsigned mk = (head < 16) ? cand[base + head] : 0xFFFFFFFFu;
            int ml = l8;
            #pragma unroll
            for (int off = 1; off < 8; off <<= 1) {
                const unsigned ok = __shfl_xor(mk, off);
                const int      ol = __shfl_xor(ml, off);
                if (ok < mk) { mk = ok; ml = ol; }
            }
            if (r == sub) myj = (int)(mk & 0x3FFFu);
            if (ml == l8) ++head;
        }
    }

    // phase 2: exact fp32 distance for this lane's candidate
    const int j = myj;
    float dot = 0.0f;
    #pragma clang loop unroll_count(4)
    for (int k = 0; k < DIM; k += 4) {
        float4 a = *(const float4*)&h0[(size_t)row * DIM + k];
        float4 b = *(const float4*)&h0[(size_t)j * DIM + k];
        dot += a.x*b.x + a.y*b.y + a.z*b.z + a.w*b.w;
    }
    float d = sq[row] + sq[j] - 2.0f * dot;

    // phase 3: 16 knockout rounds -> nbr + indeg
    const int ji = j;
    for (int t = 0; t < 16; ++t) {
        float md = d; int mi = ji;
        #pragma unroll
        for (int off = 1; off < 32; off <<= 1) {
            const float od = __shfl_xor(md, off);
            const int   oi = __shfl_xor(mi, off);
            if (od < md || (od == md && oi < mi)) { md = od; mi = oi; }
        }
        if (d == md && ji == mi) d = 3e38f;
        if (sub == 0) {
            nbr[(size_t)row * KNN + t] = mi;
            atomicAdd(&indeg[mi], 1);
        }
    }
}

// ======================================================================
// Graph build
// ======================================================================
__global__ __launch_bounds__(1024)
void scan_k(const int* __restrict__ indeg, int* __restrict__ offs,
            float* __restrict__ dinv)
{
    __shared__ int part[1024];
    const int t = threadIdx.x;
    int pre[16]; int s = 0;
    #pragma unroll
    for (int j = 0; j < 16; ++j) { pre[j] = s; s += indeg[t*16 + j]; }
    part[t] = s;
    __syncthreads();
    for (int d = 1; d < 1024; d <<= 1) {
        int v = (t >= d) ? part[t - d] : 0;
        __syncthreads();
        part[t] += v;
        __syncthreads();
    }
    const int base = (t > 0) ? part[t-1] : 0;
    #pragma unroll
    for (int j = 0; j < 16; ++j) {
        offs[t*16 + j] = base + pre[j];
        dinv[t*16 + j] = rsqrtf((float)(indeg[t*16 + j] + KNN + 1));
    }
}

__global__ void fill_k(const int* __restrict__ nbr, const int* __restrict__ offs,
                       int* __restrict__ cursor, int* __restrict__ rev)
{
    const int e = blockIdx.x * 256 + threadIdx.x;
    const int v = nbr[e];
    const int i = e >> 4;
    const int p = atomicAdd(&cursor[v], 1);
    rev[offs[v] + p] = i;
}

// ======================================================================
// GCN aggregation, bf16 in / bf16 out. ONE VERTEX PER BLOCK:
// 32 feature-lanes x 8 degree-parallel groups, fixed-order LDS reduce.
// ======================================================================
__device__ __forceinline__ void acc_row8(float (&acc)[8], const unsigned short* p)
{
    const uint4 u = *(const uint4*)p;
    acc[0] += __uint_as_float(u.x << 16);
    acc[1] += __uint_as_float(u.x & 0xffff0000u);
    acc[2] += __uint_as_float(u.y << 16);
    acc[3] += __uint_as_float(u.y & 0xffff0000u);
    acc[4] += __uint_as_float(u.z << 16);
    acc[5] += __uint_as_float(u.z & 0xffff0000u);
    acc[6] += __uint_as_float(u.w << 16);
    acc[7] += __uint_as_float(u.w & 0xffff0000u);
}

__global__ __launch_bounds__(256)
void gatherv_k(const unsigned short* __restrict__ mb, const int* __restrict__ nbr,
               const int* __restrict__ rev, const int* __restrict__ offs,
               const int* __restrict__ indeg, const float* __restrict__ dinv,
               const float* __restrict__ bias, unsigned short* __restrict__ outb)
{
    __shared__ float red[8][256];
    const int v   = blockIdx.x;
    const int tid = threadIdx.x;
    const int grp = tid >> 5;
    const int sub = tid & 31;
    const int f0  = sub * 8;

    float acc[8] = {};
    #pragma clang loop unroll(disable)
    for (int t = grp; t < 17; t += 8) {
        const int u = (t == 16) ? v : nbr[(size_t)v * KNN + t];
        acc_row8(acc, &mb[(size_t)u * DIM + f0]);
    }
    const int o = offs[v], n = indeg[v];
    #pragma clang loop unroll_count(2)
    for (int t = grp; t < n; t += 8) {
        acc_row8(acc, &mb[(size_t)rev[o + t] * DIM + f0]);
    }

    #pragma unroll
    for (int e = 0; e < 8; ++e) red[grp][f0 + e] = acc[e];
    __syncthreads();

    float s = 0.0f;
    #pragma unroll
    for (int g2 = 0; g2 < 8; ++g2) s += red[g2][tid];
    const float r = dinv[v] * s + bias[tid];
    outb[(size_t)v * DIM + tid] = f2bf(fmaxf(r, 0.0f));
}

// ======================================================================
// FC2: coalesced, 8 rows per 256-block, shfl-reduce over 32 lanes
// ======================================================================
__global__ __launch_bounds__(256)
void fc2_k(const float* __restrict__ hid, const float* __restrict__ W,
           const float* __restrict__ b, float* __restrict__ out)
{
    __shared__ float Ws[1280];
    __shared__ float bs[16];
    const int tid = threadIdx.x;
    for (int i = tid; i < 1280; i += 256) Ws[i] = W[i];
    if (tid < 10) bs[tid] = b[tid];
    __syncthreads();
    const int row = blockIdx.x * 8 + (tid >> 5);
    const int sub = tid & 31;
    float4 h4 = *(const float4*)&hid[(size_t)row * 128 + sub * 4];
    float a[10];
    #pragma unroll
    for (int c = 0; c < 10; ++c) {
        float4 w4 = *(const float4*)&Ws[c * 128 + sub * 4];
        a[c] = h4.x*w4.x + h4.y*w4.y + h4.z*w4.z + h4.w*w4.w;
    }
    #pragma unroll
    for (int off = 16; off >= 1; off >>= 1)
        #pragma unroll
        for (int c = 0; c < 10; ++c) a[c] += __shfl_down(a[c], off, 32);
    if (sub == 0) {
        #pragma unroll
        for (int c = 0; c < 10; ++c) out[(size_t)row * 10 + c] = a[c] + bs[c];
    }
}

// ======================================================================
extern "C" void kernel_launch(void* const* d_in, const int* in_sizes, int n_in,
                              void* d_out, int out_size, void* d_ws, size_t ws_size,
                              hipStream_t stream)
{
    const float* x     = (const float*)d_in[0];
    const float* Wpre  = (const float*)d_in[1];
    const float* bpre  = (const float*)d_in[2];
    const float* Wconv = (const float*)d_in[3];   // [2][256][256]
    const float* bconv = (const float*)d_in[4];   // [2][256]
    const float* Wfc1  = (const float*)d_in[5];   // [128][256]
    const float* bfc1  = (const float*)d_in[6];
    const float* Wfc2  = (const float*)d_in[7];   // [10][128]
    const float* bfc2  = (const float*)d_in[8];
    float* out = (float*)d_out;

    float* ws    = (float*)d_ws;
    float* h0    = ws;                               // NN*DIM f32 (later m2b bf16)
    float* mbuf  = h0    + (size_t)NN*DIM;           // NN*DIM  (xh/xl early, m1b later)
    float* hfbuf = mbuf  + (size_t)NN*DIM;           // NN*DIM  (cand early, hf_b/hf2_b later)
    float* hid   = hfbuf + (size_t)NN*DIM;           // NN*128  (h0b early, hid late)
    float* sqv   = hid   + (size_t)NN*128;           // NN
    float* dinv  = sqv   + NN;                       // NN
    int*   nbr   = (int*)(dinv + NN);                // NN*KNN
    int*   indeg = nbr   + (size_t)NN*KNN;           // NN
    int*   offs  = indeg + NN;                       // NN
    int*   cursor= offs  + NN;                       // NN
    int*   rev   = cursor+ NN;                       // NN*KNN
    unsigned short* wbc  = (unsigned short*)(rev + (size_t)NN*KNN);  // 2*256*256 bf16
    unsigned short* wbf1 = wbc + 2*256*256;                          // 128*256 bf16
    unsigned short* wph  = wbf1 + 128*256;                           // 256*256 bf16
    unsigned short* wpl  = wph + 256*256;                            // 256*256 bf16

    // aliases (stream-ordered safe):
    unsigned short* h0b   = (unsigned short*)hid;        // bf16(h0), dead before FC1 writes hid
    unsigned short* xh    = (unsigned short*)mbuf;       // x hi, dead after pre_mfma
    unsigned short* xl    = xh + (size_t)NN*DIM;         // x lo, dead after pre_mfma
    unsigned* cand  = (unsigned*)hfbuf;                  // SEG*NN*16 u32 (8 MB), dead after select
    unsigned short* m1b   = (unsigned short*)mbuf;       // bf16 messages L1
    unsigned short* m2b   = (unsigned short*)h0;         // bf16 messages L2 (h0 dead after select)
    unsigned short* hf_b  = (unsigned short*)hfbuf;                      // bf16 hf
    unsigned short* hf2_b = (unsigned short*)(hfbuf + (size_t)NN*DIM/2); // bf16 hf2

    hipMemsetAsync(indeg,  0, NN*sizeof(int), stream);
    hipMemsetAsync(cursor, 0, NN*sizeof(int), stream);

    // 0. conversions
    convert_hilo_k<<<NN*DIM/1024, 256, 0, stream>>>(x, xh, xl);
    convert_hilo_k<<<DIM*DIM/1024, 256, 0, stream>>>(Wpre, wph, wpl);
    convert_bf16_k<<<2*256*256/1024, 256, 0, stream>>>(Wconv, wbc);
    convert_bf16_k<<<128*256/1024,   256, 0, stream>>>(Wfc1, wbf1);

    // 1. h0 = relu(x @ Wpre^T + bpre) via split-bf16 MFMA + bf16 shadow
    pre_mfma<<<dim3(DIM/128, NN/128), 256, 0, stream>>>(
        xh, xl, wph, wpl, bpre, h0, h0b);
    // 2. row squared norms
    sq_kernel<<<NN/4, 256, 0, stream>>>(h0, sqv);
    // 3. approx 16-NN (bf16 MFMA, packed keys) -> per-seg top-16
    knn_topk<<<dim3(SEG, NN/128), 256, 0, stream>>>(h0b, sqv, cand);
    // 3b. fused merge -> refine -> nbr + indeg
    select_k<<<NN/8, 256, 0, stream>>>(cand, h0, sqv, nbr, indeg);
    // 4. graph build
    scan_k<<<1, 1024, 0, stream>>>(indeg, offs, dinv);
    fill_k<<<NN*KNN/256, 256, 0, stream>>>(nbr, offs, cursor, rev);
    // 5. GCN layer 1: m1b = bf16(dinv*(h0b @ Wc0^T)); gather -> hf_b
    gemm_mfma<false,false,true,false><<<dim3(DIM/128, NN/128), 256, 0, stream>>>(
        h0b, wbc, nullptr, dinv, nullptr, m1b, DIM);
    gatherv_k<<<NN, 256, 0, stream>>>(m1b, nbr, rev, offs, indeg, dinv, bconv, hf_b);
    // 6. GCN layer 2: m2b = bf16(dinv*(hf_b @ Wc1^T)); gather -> hf2_b
    gemm_mfma<false,false,true,false><<<dim3(DIM/128, NN/128), 256, 0, stream>>>(
        hf_b, wbc + 256*256, nullptr, dinv, nullptr, m2b, DIM);
    gatherv_k<<<NN, 256, 0, stream>>>(m2b, nbr, rev, offs, indeg, dinv, bconv + DIM, hf2_b);
    // 7. FC1: hid = relu(hf2_b @ Wfc1^T + b) f32
    gemm_mfma<true,true,false,true><<<dim3(128/128, NN/128), 256, 0, stream>>>(
        hf2_b, wbf1, bfc1, nullptr, hid, nullptr, 128);
    // 8. FC2
    fc2_k<<<NN/8, 256, 0, stream>>>(hid, Wfc2, bfc2, out);
}

// Round 15
// 807.881 us; speedup vs baseline: 1.7571x; 1.0116x over previous
//
#include <hip/hip_runtime.h>

#define NN   16384
#define DIM  256
#define KNN  16
#define SEG  8
#define JT_PER (NN / SEG / 128)   // 16 column tiles per segment

typedef __attribute__((ext_vector_type(8))) short  bf16x8;
typedef __attribute__((ext_vector_type(4))) float  f32x4;

// ======================================================================
// async global->LDS 16B helper (linear LDS dest, per-lane global source)
// ======================================================================
__device__ __forceinline__ void gload_lds16b(const unsigned short* g, void* l)
{
    __builtin_amdgcn_global_load_lds(
        (const __attribute__((address_space(1))) unsigned int*)g,
        (__attribute__((address_space(3))) unsigned int*)l, 16, 0, 0);
}

// float -> bf16 (RNE, finite inputs)
__device__ __forceinline__ unsigned short f2bf(float x)
{
    unsigned int u = __float_as_uint(x);
    unsigned int r = (u + 0x7fffu + ((u >> 16) & 1u)) >> 16;
    return (unsigned short)r;
}
__device__ __forceinline__ float bf2f(unsigned short u)
{
    return __uint_as_float(((unsigned)u) << 16);
}

// pack (distance, col) into one sortable u32: 18 d-bits | 14 j-bits
__device__ __forceinline__ unsigned pack_key(float d, int j)
{
    return (__float_as_uint(fmaxf(d, 0.0f)) & 0xFFFFC000u) | (unsigned)j;
}

// ======================================================================
// fp32 -> bf16 convert
// ======================================================================
__global__ __launch_bounds__(256)
void convert_bf16_k(const float* __restrict__ in, unsigned short* __restrict__ out)
{
    const int i4 = blockIdx.x * 256 + threadIdx.x;
    float4 v = *(const float4*)&in[(size_t)i4 * 4];
    ushort4 b;
    b.x = f2bf(v.x); b.y = f2bf(v.y); b.z = f2bf(v.z); b.w = f2bf(v.w);
    *(ushort4*)&out[(size_t)i4 * 4] = b;
}

// fp32 -> (hi, lo) bf16 split: v ~= hi + lo
__global__ __launch_bounds__(256)
void convert_hilo_k(const float* __restrict__ in,
                    unsigned short* __restrict__ hi, unsigned short* __restrict__ lo)
{
    const int i4 = blockIdx.x * 256 + threadIdx.x;
    float4 v = *(const float4*)&in[(size_t)i4 * 4];
    ushort4 h, l;
    h.x = f2bf(v.x); l.x = f2bf(v.x - bf2f(h.x));
    h.y = f2bf(v.y); l.y = f2bf(v.y - bf2f(h.y));
    h.z = f2bf(v.z); l.z = f2bf(v.z - bf2f(h.z));
    h.w = f2bf(v.w); l.w = f2bf(v.w - bf2f(h.w));
    *(ushort4*)&hi[(size_t)i4 * 4] = h;
    *(ushort4*)&lo[(size_t)i4 * 4] = l;
}

// ======================================================================
// Split-bf16 MFMA pre-GEMM:  h0 = relu( (xh+xl) @ (Wh+Wl)^T + b )
// = xh*Wh + xl*Wh + xh*Wl.  Emits f32 h0 + bf16 shadow.
// ======================================================================
__global__ __launch_bounds__(256, 1)
void pre_mfma(const unsigned short* __restrict__ xh, const unsigned short* __restrict__ xl,
              const unsigned short* __restrict__ wh, const unsigned short* __restrict__ wl,
              const float* __restrict__ bias,
              float* __restrict__ C, unsigned short* __restrict__ Cb)
{
    __shared__ __align__(16) float smem[16896];              // 67.6 KB
    unsigned short* stAh = (unsigned short*)smem;
    unsigned short* stAl = (unsigned short*)((char*)smem + 16384);
    unsigned short* stBh = (unsigned short*)((char*)smem + 32768);
    unsigned short* stBl = (unsigned short*)((char*)smem + 49152);
    float* D = smem;                                         // f32 [128][132]

    const int tid  = threadIdx.x;
    const int lane = tid & 63;
    const int wave = tid >> 6;
    const int wj = wave >> 1;
    const int wi = wave & 1;
    const int l15 = lane & 15;
    const int g   = lane >> 4;
    const int R0 = blockIdx.y * 128;
    const int C0 = blockIdx.x * 128;

    f32x4 acc[4][4];
    #pragma unroll
    for (int fa = 0; fa < 4; ++fa)
        #pragma unroll
        for (int fb = 0; fb < 4; ++fb)
            acc[fa][fb] = (f32x4){0.f, 0.f, 0.f, 0.f};

    #pragma unroll 1
    for (int ch = 0; ch < 4; ++ch) {
        const int k0g = ch * 64;
        __syncthreads();
        #pragma unroll
        for (int it = 0; it < 4; ++it) {
            const int lin = tid + it * 256;
            const int row = lin >> 3, f = lin & 7;
            const int kq = f ^ (row & 7);
            gload_lds16b(&xh[(size_t)(R0 + row) * 256 + k0g + kq * 8], (char*)stAh + lin * 16);
            gload_lds16b(&xl[(size_t)(R0 + row) * 256 + k0g + kq * 8], (char*)stAl + lin * 16);
            gload_lds16b(&wh[(size_t)(C0 + row) * 256 + k0g + kq * 8], (char*)stBh + lin * 16);
            gload_lds16b(&wl[(size_t)(C0 + row) * 256 + k0g + kq * 8], (char*)stBl + lin * 16);
        }
        __syncthreads();

        #pragma unroll
        for (int k0 = 0; k0 < 64; k0 += 32) {
            const int ub = (k0 >> 3) + g;
            bf16x8 afh[4], afl[4], bfh[4], bfl[4];
            #pragma unroll
            for (int q = 0; q < 4; ++q) {
                const int jr = wj*64 + q*16 + l15;
                const int ir = wi*64 + q*16 + l15;
                const int oj = (ub ^ (jr & 7)) * 16;
                const int oi = (ub ^ (ir & 7)) * 16;
                afh[q] = *(const bf16x8*)((char*)stBh + jr*128 + oj);
                afl[q] = *(const bf16x8*)((char*)stBl + jr*128 + oj);
                bfh[q] = *(const bf16x8*)((char*)stAh + ir*128 + oi);
                bfl[q] = *(const bf16x8*)((char*)stAl + ir*128 + oi);
            }
            #pragma unroll
            for (int fa = 0; fa < 4; ++fa)
                #pragma unroll
                for (int fb = 0; fb < 4; ++fb) {
                    acc[fa][fb] = __builtin_amdgcn_mfma_f32_16x16x32_bf16(
                        afh[fa], bfl[fb], acc[fa][fb], 0, 0, 0);
                    acc[fa][fb] = __builtin_amdgcn_mfma_f32_16x16x32_bf16(
                        afl[fa], bfh[fb], acc[fa][fb], 0, 0, 0);
                    acc[fa][fb] = __builtin_amdgcn_mfma_f32_16x16x32_bf16(
                        afh[fa], bfh[fb], acc[fa][fb], 0, 0, 0);
                }
        }
    }

    __syncthreads();
    #pragma unroll
    for (int fa = 0; fa < 4; ++fa)
        #pragma unroll
        for (int fb = 0; fb < 4; ++fb) {
            const int i_ = wi*64 + fb*16 + l15;
            const int j0 = wj*64 + fa*16 + g*4;
            *(f32x4*)&D[i_ * 132 + j0] = acc[fa][fb];
        }
    __syncthreads();

    #pragma unroll
    for (int it = 0; it < 16; ++it) {
        const int linear = it * 256 + tid;
        const int r = linear >> 5, c4 = linear & 31;
        float4 v = *(const float4*)&D[r * 132 + c4 * 4];
        float o[4] = {v.x, v.y, v.z, v.w};
        #pragma unroll
        for (int cc = 0; cc < 4; ++cc) {
            o[cc] += bias[C0 + c4*4 + cc];
            o[cc] = fmaxf(o[cc], 0.0f);
        }
        *(float4*)&C[(size_t)(R0 + r) * 256 + C0 + c4*4] =
            make_float4(o[0], o[1], o[2], o[3]);
        ushort4 bv;
        bv.x = f2bf(o[0]); bv.y = f2bf(o[1]);
        bv.z = f2bf(o[2]); bv.w = f2bf(o[3]);
        *(ushort4*)&Cb[(size_t)(R0 + r) * 256 + C0 + c4*4] = bv;
    }
}

// ======================================================================
// bf16-MFMA GEMM: out = act( rowscale*(Ab @ Wb^T) + bias ), K = 256.
// ======================================================================
template<bool RELU, bool BIAS, bool ROWSCALE, bool F32OUT>
__global__ __launch_bounds__(256, 1)
void gemm_mfma(const unsigned short* __restrict__ Ab, const unsigned short* __restrict__ Wb,
               const float* __restrict__ bias, const float* __restrict__ rscale,
               float* __restrict__ C, unsigned short* __restrict__ Cb, int NO)
{
    __shared__ __align__(16) float smem[25088];            // 98 KB
    unsigned short* stA = (unsigned short*)smem;
    unsigned short* stB = (unsigned short*)(smem + 4096);
    float* D = smem + 8192;

    const int tid  = threadIdx.x;
    const int lane = tid & 63;
    const int wave = tid >> 6;
    const int wj = wave >> 1;
    const int wi = wave & 1;
    const int l15 = lane & 15;
    const int g   = lane >> 4;
    const int R0 = blockIdx.y * 128;
    const int C0 = blockIdx.x * 128;

    f32x4 acc[4][4];
    #pragma unroll
    for (int fa = 0; fa < 4; ++fa)
        #pragma unroll
        for (int fb = 0; fb < 4; ++fb)
            acc[fa][fb] = (f32x4){0.f, 0.f, 0.f, 0.f};

    #pragma unroll 1
    for (int ch = 0; ch < 4; ++ch) {
        const int k0g = ch * 64;
        __syncthreads();
        #pragma unroll
        for (int it = 0; it < 4; ++it) {
            const int lin = tid + it * 256;
            const int row = lin >> 3, f = lin & 7;
            const int kq = f ^ (row & 7);
            gload_lds16b(&Ab[(size_t)(R0 + row) * 256 + k0g + kq * 8],
                         (char*)stA + lin * 16);
            gload_lds16b(&Wb[(size_t)(C0 + row) * 256 + k0g + kq * 8],
                         (char*)stB + lin * 16);
        }
        __syncthreads();

        #pragma unroll
        for (int k0 = 0; k0 < 64; k0 += 32) {
            const int ub = (k0 >> 3) + g;
            bf16x8 af[4], bf[4];
            #pragma unroll
            for (int fb = 0; fb < 4; ++fb) {
                const int jr = wj*64 + fb*16 + l15;
                const int ir = wi*64 + fb*16 + l15;
                af[fb] = *(const bf16x8*)((char*)stB + jr*128 + ((ub ^ (jr & 7)) * 16));
                bf[fb] = *(const bf16x8*)((char*)stA + ir*128 + ((ub ^ (ir & 7)) * 16));
            }
            #pragma unroll
            for (int fa = 0; fa < 4; ++fa)
                #pragma unroll
                for (int fb = 0; fb < 4; ++fb)
                    acc[fa][fb] = __builtin_amdgcn_mfma_f32_16x16x32_bf16(
                        af[fa], bf[fb], acc[fa][fb], 0, 0, 0);
        }
    }

    #pragma unroll
    for (int fa = 0; fa < 4; ++fa)
        #pragma unroll
        for (int fb = 0; fb < 4; ++fb) {
            const int i_ = wi*64 + fb*16 + l15;
            const int j0 = wj*64 + fa*16 + g*4;
            *(f32x4*)&D[i_ * 132 + j0] = acc[fa][fb];
        }
    __syncthreads();

    #pragma unroll
    for (int it = 0; it < 16; ++it) {
        const int linear = it * 256 + tid;
        const int r = linear >> 5, c4 = linear & 31;
        float4 v = *(const float4*)&D[r * 132 + c4 * 4];
        const float s = ROWSCALE ? rscale[R0 + r] : 1.0f;
        float o[4] = {v.x * s, v.y * s, v.z * s, v.w * s};
        #pragma unroll
        for (int cc = 0; cc < 4; ++cc) {
            if (BIAS) o[cc] += bias[C0 + c4*4 + cc];
            if (RELU) o[cc] = fmaxf(o[cc], 0.0f);
        }
        if (F32OUT) {
            *(float4*)&C[(size_t)(R0 + r) * NO + C0 + c4*4] =
                make_float4(o[0], o[1], o[2], o[3]);
        } else {
            ushort4 bv;
            bv.x = f2bf(o[0]); bv.y = f2bf(o[1]);
            bv.z = f2bf(o[2]); bv.w = f2bf(o[3]);
            *(ushort4*)&Cb[(size_t)(R0 + r) * NO + C0 + c4*4] = bv;
        }
    }
}

// ======================================================================
// Row squared-norms
// ======================================================================
__global__ __launch_bounds__(256)
void sq_kernel(const float* __restrict__ h0, float* __restrict__ sq)
{
    const int wid = threadIdx.x >> 6, lane = threadIdx.x & 63;
    const int row = blockIdx.x * 4 + wid;
    float4 v = *(const float4*)&h0[(size_t)row * DIM + lane * 4];
    float s = v.x*v.x + v.y*v.y + v.z*v.z + v.w*v.w;
    #pragma unroll
    for (int o = 32; o > 0; o >>= 1) s += __shfl_down(s, o);
    if (lane == 0) sq[row] = s;
}

// ======================================================================
// Packed-key top-16 insert: sorted-ascending bubble pass, u32 min/max
// ======================================================================
__device__ __forceinline__ void key_insert(unsigned (&kl)[16], unsigned k)
{
    #pragma unroll
    for (int p = 0; p < 16; ++p) {
        const unsigned lo = min(kl[p], k);
        k = max(kl[p], k);
        kl[p] = lo;
    }
}

// ======================================================================
// kNN approx pass (round-12 config -- best measured: 467 us, no spill,
// conflicts 255K). bf16 MFMA 128x128 Gram tiles, TWO 64-col D phases
// (D = [128][68] f32, 34.8 KB LDS), packed-key register top-16.
// Residency probes exhausted: 32 KB LDS did not raise occupancy (r14);
// fewer/bigger blocks regressed (r11); this is the structural floor.
// ======================================================================
__global__ __launch_bounds__(256, 3)
void knn_topk(const unsigned short* __restrict__ h0b, const float* __restrict__ sq,
              unsigned* __restrict__ cand)
{
    __shared__ __align__(16) float smem[8704];   // 34.8 KB
    char* sbase = (char*)smem;
    unsigned short* stA = (unsigned short*)sbase;            // i rows, bf16[128][64]
    unsigned short* stB = (unsigned short*)(sbase + 16384);  // j rows, bf16[128][64]
    float* D = smem;                                         // f32 [128 i][68]

    const int tid  = threadIdx.x;
    const int lane = tid & 63;
    const int wave = tid >> 6;
    const int wj = wave >> 1;
    const int wi = wave & 1;
    const int l15 = lane & 15;
    const int g   = lane >> 4;
    const int R0 = blockIdx.y * 128;
    const int seg = blockIdx.x;

    const int orow  = tid >> 1;
    const int ohalf = tid & 1;
    const int myrow = R0 + orow;
    const float osq = sq[myrow];

    unsigned kl[16];
    #pragma unroll
    for (int e = 0; e < 16; ++e) kl[e] = 0xFFFFFFFFu;

    for (int jt = 0; jt < JT_PER; ++jt) {
        const int C0 = seg * (NN / SEG) + jt * 128;
        const bool diag = (C0 == R0);          // wave-uniform
        f32x4 acc[4][4];
        #pragma unroll
        for (int fa = 0; fa < 4; ++fa)
            #pragma unroll
            for (int fb = 0; fb < 4; ++fb)
                acc[fa][fb] = (f32x4){0.f, 0.f, 0.f, 0.f};

        #pragma unroll 1
        for (int ch = 0; ch < 4; ++ch) {
            const int k0g = ch * 64;
            __syncthreads();
            #pragma unroll
            for (int it = 0; it < 4; ++it) {
                const int lin = tid + it * 256;
                const int row = lin >> 3, f = lin & 7;
                const int kq = f ^ (row & 7);
                gload_lds16b(&h0b[(size_t)(R0 + row) * DIM + k0g + kq * 8],
                             (char*)stA + lin * 16);
                gload_lds16b(&h0b[(size_t)(C0 + row) * DIM + k0g + kq * 8],
                             (char*)stB + lin * 16);
            }
            __syncthreads();

            #pragma unroll
            for (int k0 = 0; k0 < 64; k0 += 32) {
                const int ub = (k0 >> 3) + g;
                bf16x8 af[4], bf[4];
                #pragma unroll
                for (int fb = 0; fb < 4; ++fb) {
                    const int jr = wj*64 + fb*16 + l15;
                    const int ir = wi*64 + fb*16 + l15;
                    af[fb] = *(const bf16x8*)((char*)stB + jr*128 + ((ub ^ (jr & 7)) * 16));
                    bf[fb] = *(const bf16x8*)((char*)stA + ir*128 + ((ub ^ (ir & 7)) * 16));
                }
                #pragma unroll
                for (int fa = 0; fa < 4; ++fa)
                    #pragma unroll
                    for (int fb = 0; fb < 4; ++fb)
                        acc[fa][fb] = __builtin_amdgcn_mfma_f32_16x16x32_bf16(
                            af[fa], bf[fb], acc[fa][fb], 0, 0, 0);
            }
        }

        // two 64-col dump/scan phases (D = [128][68] f32)
        #pragma unroll
        for (int h = 0; h < 2; ++h) {
            __syncthreads();
            if (wj == h) {
                #pragma unroll
                for (int fa = 0; fa < 4; ++fa)
                    #pragma unroll
                    for (int fb = 0; fb < 4; ++fb) {
                        const int i_ = wi*64 + fb*16 + l15;
                        *(f32x4*)&D[i_ * 68 + fa*16 + g*4] = acc[fa][fb];
                    }
            }
            __syncthreads();

            const int cb = C0 + h*64 + ohalf*32;
            const float* Dr = &D[orow * 68 + ohalf * 32];
            #pragma clang loop unroll(disable)
            for (int e = 0; e < 8; ++e) {
                const float4 dv4 = *(const float4*)&Dr[e * 4];
                const float4 sv4 = *(const float4*)&sq[cb + e * 4];
                const int j0 = cb + e * 4;
                unsigned k0 = pack_key((osq + sv4.x) - 2.0f * dv4.x, j0 + 0);
                unsigned k1 = pack_key((osq + sv4.y) - 2.0f * dv4.y, j0 + 1);
                unsigned k2 = pack_key((osq + sv4.z) - 2.0f * dv4.z, j0 + 2);
                unsigned k3 = pack_key((osq + sv4.w) - 2.0f * dv4.w, j0 + 3);
                if (diag) {          // self-exclusion only in the diagonal tile
                    if (j0 + 0 == myrow) k0 = 0xFFFFFFFFu;
                    if (j0 + 1 == myrow) k1 = 0xFFFFFFFFu;
                    if (j0 + 2 == myrow) k2 = 0xFFFFFFFFu;
                    if (j0 + 3 == myrow) k3 = 0xFFFFFFFFu;
                }
                const unsigned kmin = min(min(k0, k1), min(k2, k3));
                if (kmin < kl[15]) {
                    if (k0 < kl[15]) key_insert(kl, k0);
                    if (k1 < kl[15]) key_insert(kl, k1);
                    if (k2 < kl[15]) key_insert(kl, k2);
                    if (k3 < kl[15]) key_insert(kl, k3);
                }
            }
        }
    }

    // block-level merge: 2 sorted half-lists per row -> sorted 16 per (seg,row)
    __syncthreads();
    unsigned* ck = (unsigned*)smem;     // [256][17] u32 = 17.4 KB
    #pragma unroll
    for (int e = 0; e < 16; ++e) ck[tid * 17 + e] = kl[e];
    __syncthreads();
    if (tid < 128) {
        const unsigned* LA = &ck[(2*tid) * 17];
        const unsigned* LB = &ck[(2*tid + 1) * 17];
        int pa = 0, pb = 0;
        const size_t obase = ((size_t)seg * NN + R0 + tid) * 16;
        #pragma clang loop unroll(disable)
        for (int r = 0; r < 16; ++r) {
            const unsigned ka = LA[pa], kb = LB[pb];
            const bool takeA = (ka < kb);
            cand[obase + r] = takeA ? ka : kb;
            if (takeA) ++pa; else ++pb;
        }
    }
}

// ======================================================================
// Fused select: 8-way merge (register-resident, no LDS) -> top-32
// candidates -> exact fp32 refine -> nbr + indeg atomics.
// ======================================================================
__global__ __launch_bounds__(256)
void select_k(const unsigned* __restrict__ cand, const float* __restrict__ h0,
              const float* __restrict__ sq, int* __restrict__ nbr,
              int* __restrict__ indeg)
{
    const int tid = threadIdx.x;
    const int sub = tid & 31;
    const int row = blockIdx.x * 8 + (tid >> 5);

    // phase 1: merge 8 sorted seg lists; lane sub keeps the sub-th winner
    int myj = 0;
    {
        const int l8 = sub & 7;
        const size_t base = ((size_t)l8 * NN + row) * 16;
        int head = 0;
        #pragma clang loop unroll(disable)
        for (int r = 0; r < 32; ++r) {
            unsigned mk = (head < 16) ? cand[base + head] : 0xFFFFFFFFu;
            int ml = l8;
            #pragma unroll
            for (int off = 1; off < 8; off <<= 1) {
                const unsigned ok = __shfl_xor(mk, off);
                const int      ol = __shfl_xor(ml, off);
                if (ok < mk) { mk = ok; ml = ol; }
            }
            if (r == sub) myj = (int)(mk & 0x3FFFu);
            if (ml == l8) ++head;
        }
    }

    // phase 2: exact fp32 distance for this lane's candidate
    const int j = myj;
    float dot = 0.0f;
    #pragma clang loop unroll_count(4)
    for (int k = 0; k < DIM; k += 4) {
        float4 a = *(const float4*)&h0[(size_t)row * DIM + k];
        float4 b = *(const float4*)&h0[(size_t)j * DIM + k];
        dot += a.x*b.x + a.y*b.y + a.z*b.z + a.w*b.w;
    }
    float d = sq[row] + sq[j] - 2.0f * dot;

    // phase 3: 16 knockout rounds -> nbr + indeg
    const int ji = j;
    for (int t = 0; t < 16; ++t) {
        float md = d; int mi = ji;
        #pragma unroll
        for (int off = 1; off < 32; off <<= 1) {
            const float od = __shfl_xor(md, off);
            const int   oi = __shfl_xor(mi, off);
            if (od < md || (od == md && oi < mi)) { md = od; mi = oi; }
        }
        if (d == md && ji == mi) d = 3e38f;
        if (sub == 0) {
            nbr[(size_t)row * KNN + t] = mi;
            atomicAdd(&indeg[mi], 1);
        }
    }
}

// ======================================================================
// Graph build
// ======================================================================
__global__ __launch_bounds__(1024)
void scan_k(const int* __restrict__ indeg, int* __restrict__ offs,
            float* __restrict__ dinv)
{
    __shared__ int part[1024];
    const int t = threadIdx.x;
    int pre[16]; int s = 0;
    #pragma unroll
    for (int j = 0; j < 16; ++j) { pre[j] = s; s += indeg[t*16 + j]; }
    part[t] = s;
    __syncthreads();
    for (int d = 1; d < 1024; d <<= 1) {
        int v = (t >= d) ? part[t - d] : 0;
        __syncthreads();
        part[t] += v;
        __syncthreads();
    }
    const int base = (t > 0) ? part[t-1] : 0;
    #pragma unroll
    for (int j = 0; j < 16; ++j) {
        offs[t*16 + j] = base + pre[j];
        dinv[t*16 + j] = rsqrtf((float)(indeg[t*16 + j] + KNN + 1));
    }
}

__global__ void fill_k(const int* __restrict__ nbr, const int* __restrict__ offs,
                       int* __restrict__ cursor, int* __restrict__ rev)
{
    const int e = blockIdx.x * 256 + threadIdx.x;
    const int v = nbr[e];
    const int i = e >> 4;
    const int p = atomicAdd(&cursor[v], 1);
    rev[offs[v] + p] = i;
}

// ======================================================================
// GCN aggregation, bf16 in / bf16 out. ONE VERTEX PER BLOCK:
// 32 feature-lanes x 8 degree-parallel groups, fixed-order LDS reduce.
// ======================================================================
__device__ __forceinline__ void acc_row8(float (&acc)[8], const unsigned short* p)
{
    const uint4 u = *(const uint4*)p;
    acc[0] += __uint_as_float(u.x << 16);
    acc[1] += __uint_as_float(u.x & 0xffff0000u);
    acc[2] += __uint_as_float(u.y << 16);
    acc[3] += __uint_as_float(u.y & 0xffff0000u);
    acc[4] += __uint_as_float(u.z << 16);
    acc[5] += __uint_as_float(u.z & 0xffff0000u);
    acc[6] += __uint_as_float(u.w << 16);
    acc[7] += __uint_as_float(u.w & 0xffff0000u);
}

__global__ __launch_bounds__(256)
void gatherv_k(const unsigned short* __restrict__ mb, const int* __restrict__ nbr,
               const int* __restrict__ rev, const int* __restrict__ offs,
               const int* __restrict__ indeg, const float* __restrict__ dinv,
               const float* __restrict__ bias, unsigned short* __restrict__ outb)
{
    __shared__ float red[8][256];
    const int v   = blockIdx.x;
    const int tid = threadIdx.x;
    const int grp = tid >> 5;
    const int sub = tid & 31;
    const int f0  = sub * 8;

    float acc[8] = {};
    #pragma clang loop unroll(disable)
    for (int t = grp; t < 17; t += 8) {
        const int u = (t == 16) ? v : nbr[(size_t)v * KNN + t];
        acc_row8(acc, &mb[(size_t)u * DIM + f0]);
    }
    const int o = offs[v], n = indeg[v];
    #pragma clang loop unroll_count(2)
    for (int t = grp; t < n; t += 8) {
        acc_row8(acc, &mb[(size_t)rev[o + t] * DIM + f0]);
    }

    #pragma unroll
    for (int e = 0; e < 8; ++e) red[grp][f0 + e] = acc[e];
    __syncthreads();

    float s = 0.0f;
    #pragma unroll
    for (int g2 = 0; g2 < 8; ++g2) s += red[g2][tid];
    const float r = dinv[v] * s + bias[tid];
    outb[(size_t)v * DIM + tid] = f2bf(fmaxf(r, 0.0f));
}

// ======================================================================
// FC2: coalesced, 8 rows per 256-block, shfl-reduce over 32 lanes
// ======================================================================
__global__ __launch_bounds__(256)
void fc2_k(const float* __restrict__ hid, const float* __restrict__ W,
           const float* __restrict__ b, float* __restrict__ out)
{
    __shared__ float Ws[1280];
    __shared__ float bs[16];
    const int tid = threadIdx.x;
    for (int i = tid; i < 1280; i += 256) Ws[i] = W[i];
    if (tid < 10) bs[tid] = b[tid];
    __syncthreads();
    const int row = blockIdx.x * 8 + (tid >> 5);
    const int sub = tid & 31;
    float4 h4 = *(const float4*)&hid[(size_t)row * 128 + sub * 4];
    float a[10];
    #pragma unroll
    for (int c = 0; c < 10; ++c) {
        float4 w4 = *(const float4*)&Ws[c * 128 + sub * 4];
        a[c] = h4.x*w4.x + h4.y*w4.y + h4.z*w4.z + h4.w*w4.w;
    }
    #pragma unroll
    for (int off = 16; off >= 1; off >>= 1)
        #pragma unroll
        for (int c = 0; c < 10; ++c) a[c] += __shfl_down(a[c], off, 32);
    if (sub == 0) {
        #pragma unroll
        for (int c = 0; c < 10; ++c) out[(size_t)row * 10 + c] = a[c] + bs[c];
    }
}

// ======================================================================
extern "C" void kernel_launch(void* const* d_in, const int* in_sizes, int n_in,
                              void* d_out, int out_size, void* d_ws, size_t ws_size,
                              hipStream_t stream)
{
    const float* x     = (const float*)d_in[0];
    const float* Wpre  = (const float*)d_in[1];
    const float* bpre  = (const float*)d_in[2];
    const float* Wconv = (const float*)d_in[3];   // [2][256][256]
    const float* bconv = (const float*)d_in[4];   // [2][256]
    const float* Wfc1  = (const float*)d_in[5];   // [128][256]
    const float* bfc1  = (const float*)d_in[6];
    const float* Wfc2  = (const float*)d_in[7];   // [10][128]
    const float* bfc2  = (const float*)d_in[8];
    float* out = (float*)d_out;

    float* ws    = (float*)d_ws;
    float* h0    = ws;                               // NN*DIM f32 (later m2b bf16)
    float* mbuf  = h0    + (size_t)NN*DIM;           // NN*DIM  (xh/xl early, m1b later)
    float* hfbuf = mbuf  + (size_t)NN*DIM;           // NN*DIM  (cand early, hf_b/hf2_b later)
    float* hid   = hfbuf + (size_t)NN*DIM;           // NN*128  (h0b early, hid late)
    float* sqv   = hid   + (size_t)NN*128;           // NN
    float* dinv  = sqv   + NN;                       // NN
    int*   nbr   = (int*)(dinv + NN);                // NN*KNN
    int*   indeg = nbr   + (size_t)NN*KNN;           // NN
    int*   offs  = indeg + NN;                       // NN
    int*   cursor= offs  + NN;                       // NN
    int*   rev   = cursor+ NN;                       // NN*KNN
    unsigned short* wbc  = (unsigned short*)(rev + (size_t)NN*KNN);  // 2*256*256 bf16
    unsigned short* wbf1 = wbc + 2*256*256;                          // 128*256 bf16
    unsigned short* wph  = wbf1 + 128*256;                           // 256*256 bf16
    unsigned short* wpl  = wph + 256*256;                            // 256*256 bf16

    // aliases (stream-ordered safe):
    unsigned short* h0b   = (unsigned short*)hid;        // bf16(h0), dead before FC1 writes hid
    unsigned short* xh    = (unsigned short*)mbuf;       // x hi, dead after pre_mfma
    unsigned short* xl    = xh + (size_t)NN*DIM;         // x lo, dead after pre_mfma
    unsigned* cand  = (unsigned*)hfbuf;                  // SEG*NN*16 u32 (8 MB), dead after select
    unsigned short* m1b   = (unsigned short*)mbuf;       // bf16 messages L1
    unsigned short* m2b   = (unsigned short*)h0;         // bf16 messages L2 (h0 dead after select)
    unsigned short* hf_b  = (unsigned short*)hfbuf;                      // bf16 hf
    unsigned short* hf2_b = (unsigned short*)(hfbuf + (size_t)NN*DIM/2); // bf16 hf2

    hipMemsetAsync(indeg,  0, NN*sizeof(int), stream);
    hipMemsetAsync(cursor, 0, NN*sizeof(int), stream);

    // 0. conversions
    convert_hilo_k<<<NN*DIM/1024, 256, 0, stream>>>(x, xh, xl);
    convert_hilo_k<<<DIM*DIM/1024, 256, 0, stream>>>(Wpre, wph, wpl);
    convert_bf16_k<<<2*256*256/1024, 256, 0, stream>>>(Wconv, wbc);
    convert_bf16_k<<<128*256/1024,   256, 0, stream>>>(Wfc1, wbf1);

    // 1. h0 = relu(x @ Wpre^T + bpre) via split-bf16 MFMA + bf16 shadow
    pre_mfma<<<dim3(DIM/128, NN/128), 256, 0, stream>>>(
        xh, xl, wph, wpl, bpre, h0, h0b);
    // 2. row squared norms
    sq_kernel<<<NN/4, 256, 0, stream>>>(h0, sqv);
    // 3. approx 16-NN (bf16 MFMA, packed keys) -> per-seg top-16
    knn_topk<<<dim3(SEG, NN/128), 256, 0, stream>>>(h0b, sqv, cand);
    // 3b. fused merge -> refine -> nbr + indeg
    select_k<<<NN/8, 256, 0, stream>>>(cand, h0, sqv, nbr, indeg);
    // 4. graph build
    scan_k<<<1, 1024, 0, stream>>>(indeg, offs, dinv);
    fill_k<<<NN*KNN/256, 256, 0, stream>>>(nbr, offs, cursor, rev);
    // 5. GCN layer 1: m1b = bf16(dinv*(h0b @ Wc0^T)); gather -> hf_b
    gemm_mfma<false,false,true,false><<<dim3(DIM/128, NN/128), 256, 0, stream>>>(
        h0b, wbc, nullptr, dinv, nullptr, m1b, DIM);
    gatherv_k<<<NN, 256, 0, stream>>>(m1b, nbr, rev, offs, indeg, dinv, bconv, hf_b);
    // 6. GCN layer 2: m2b = bf16(dinv*(hf_b @ Wc1^T)); gather -> hf2_b
    gemm_mfma<false,false,true,false><<<dim3(DIM/128, NN/128), 256, 0, stream>>>(
        hf_b, wbc + 256*256, nullptr, dinv, nullptr, m2b, DIM);
    gatherv_k<<<NN, 256, 0, stream>>>(m2b, nbr, rev, offs, indeg, dinv, bconv + DIM, hf2_b);
    // 7. FC1: hid = relu(hf2_b @ Wfc1^T + b) f32
    gemm_mfma<true,true,false,true><<<dim3(128/128, NN/128), 256, 0, stream>>>(
        hf2_b, wbf1, bfc1, nullptr, hid, nullptr, 128);
    // 8. FC2
    fc2_k<<<NN/8, 256, 0, stream>>>(hid, Wfc2, bfc2, out);
}